// Round 7
// baseline (307.048 us; speedup 1.0000x reference)
//
#include <hip/hip_runtime.h>
#include <math.h>

// Problem constants
#define BATCH 256
#define IC    1152   // 32*6*6 input capsule positions
#define DD    8
#define OO    10
#define EE    16
#define BTILE 64     // batches per block (one wave per o, lanes = batch)
#define NBT   4      // BATCH / BTILE
#define NT    640    // OO * BTILE threads per block (10 waves)
#define CHUNK 9      // ijk positions per block
#define NCHUNK 128   // IC / CHUNK  -> 512 blocks

// pass kernel, two-phase / two-barrier form (r6 structure), with W moved off
// the scalar pipe onto wave-uniform VMEM loads:
//  - Evidence r0/r5/r6: every s_load-W variant lands at ~45-64 us/pass with
//    VALUBusy ~15% and SGPR_Count=32 -> the scalar pipe serializes ~1440
//    x16-loads/CU/pass with ~2 in flight. VALU floor is ~5.5 us.
//  - Fix: W addresses get an opaque VGPR zero (inline asm) added, so the
//    compiler cannot prove wave-uniformity and must emit global_load_dwordx4.
//    All lanes hit the same 64B line -> 1 L1 transaction per load, broadcast;
//    deep vmcnt queue pipelines; L1/L2-resident (5 KB/ijk per block).
//    (r4 ruled out DIVERGENT per-lane VMEM W: 10-way fan-out, 3x worse.)
//  - Stage: all 9 ijk x-tiles -> LDS, barrier. Phase A: logits (folded form,
//    no u array), exp, store to LDS, barrier. Phase B: softmax + accumulate,
//    no barriers. Disjoint live sets -> uncapped alloc, no spills
//    (check: WRITE_SIZE ~21 MB, VGPR 60-90).
__global__ __launch_bounds__(NT) void caps_pass_kernel(
    const float* __restrict__ x,       // [256][1152][8]
    const float* __restrict__ W,       // [1152][10][8][16]
    const float* __restrict__ V,       // [256][10][16] accumulated v
    float* __restrict__ s_part,        // [NCHUNK][256][10][16]
    int first)
{
    __shared__ float x_lds[CHUNK][DD][BTILE];   // d-major: conflict-free reads
    __shared__ float elg_lds[CHUNK][NT];

    const int tid = threadIdx.x;
    const int o   = tid >> 6;        // wave id 0..9
    const int bl  = tid & 63;
    const int o_u = __builtin_amdgcn_readfirstlane(o);   // wave-uniform o
    const int b   = blockIdx.y * BTILE + bl;
    const int ijk0 = blockIdx.x * CHUNK;

    // opaque VGPR zero: forces W loads onto the VMEM path (global_load),
    // not the scalar s_load path. Value is 0 in every lane.
    int vzero;
    asm("v_mov_b32 %0, 0" : "=v"(vzero));

    // ---- stage: all CHUNK ijk x-tiles into LDS (coalesced float4) ----
    {
        const float* xgrp = x + (size_t)(blockIdx.y * BTILE) * (IC * DD);
        #pragma unroll 1
        for (int i = tid; i < CHUNK * BTILE * 2; i += NT) {
            const int lq = i & 1;            // which half of the 8 d's
            const int lb = (i >> 1) & 63;    // batch within tile
            const int ls = i >> 7;           // ijk within chunk
            const float4 t = *reinterpret_cast<const float4*>(
                xgrp + (size_t)lb * (IC * DD) + (size_t)(ijk0 + ls) * DD + lq * 4);
            x_lds[ls][lq * 4 + 0][lb] = t.x;
            x_lds[ls][lq * 4 + 1][lb] = t.y;
            x_lds[ls][lq * 4 + 2][lb] = t.z;
            x_lds[ls][lq * 4 + 3][lb] = t.w;
        }
    }
    __syncthreads();

    // ---- phase A (routing passes only): logits -> elg_lds ----
    if (!first) {
        // per-thread copy of V[b,o,:] (dead after phase A)
        float vreg[EE];
        const float4* vp = reinterpret_cast<const float4*>(V + ((size_t)b * OO + o) * EE);
        #pragma unroll
        for (int q = 0; q < 4; ++q) {
            float4 t = vp[q];
            vreg[q * 4 + 0] = t.x; vreg[q * 4 + 1] = t.y;
            vreg[q * 4 + 2] = t.z; vreg[q * 4 + 3] = t.w;
        }

        #pragma unroll 1
        for (int s = 0; s < CHUNK; ++s) {
            const float* wp = W + (size_t)(ijk0 + s) * (OO * DD * EE) + o_u * (DD * EE);
            const float4* wq = reinterpret_cast<const float4*>(wp) + vzero;
            float xr[DD];
            #pragma unroll
            for (int d = 0; d < DD; ++d) xr[d] = x_lds[s][d][bl];
            float lg = 0.f;
            #pragma unroll
            for (int d = 0; d < DD; ++d) {
                float t = 0.f;
                #pragma unroll
                for (int q = 0; q < 4; ++q) {
                    const float4 w4 = wq[d * 4 + q];   // uniform VMEM broadcast
                    t = fmaf(w4.x, vreg[q * 4 + 0], t);
                    t = fmaf(w4.y, vreg[q * 4 + 1], t);
                    t = fmaf(w4.z, vreg[q * 4 + 2], t);
                    t = fmaf(w4.w, vreg[q * 4 + 3], t);
                }
                lg = fmaf(xr[d], t, lg);
            }
            // logits bounded -> softmax without max subtraction (proven r1-r6)
            elg_lds[s][tid] = __expf(lg);
        }
        __syncthreads();
    }

    // ---- phase B: softmax weights + accumulate (no barriers) ----
    float sacc[EE];
    #pragma unroll
    for (int e = 0; e < EE; ++e) sacc[e] = 0.f;

    #pragma unroll 1
    for (int s = 0; s < CHUNK; ++s) {
        const float* wp = W + (size_t)(ijk0 + s) * (OO * DD * EE) + o_u * (DD * EE);
        const float4* wq = reinterpret_cast<const float4*>(wp) + vzero;
        float xr[DD];
        #pragma unroll
        for (int d = 0; d < DD; ++d) xr[d] = x_lds[s][d][bl];

        float c;
        if (!first) {
            float den = 0.f;
            #pragma unroll
            for (int oo = 0; oo < OO; ++oo)
                den += elg_lds[s][oo * 64 + bl];    // bank: bl%32, 2-way free
            c = __fdividef(elg_lds[s][o * 64 + bl], den);
        } else {
            c = 1.0f;   // uniform 0.1 folded into output mul
        }

        #pragma unroll
        for (int d = 0; d < DD; ++d) {
            const float cx = c * xr[d];
            #pragma unroll
            for (int q = 0; q < 4; ++q) {
                const float4 w4 = wq[d * 4 + q];   // uniform VMEM broadcast
                sacc[q * 4 + 0] = fmaf(cx, w4.x, sacc[q * 4 + 0]);
                sacc[q * 4 + 1] = fmaf(cx, w4.y, sacc[q * 4 + 1]);
                sacc[q * 4 + 2] = fmaf(cx, w4.z, sacc[q * 4 + 2]);
                sacc[q * 4 + 3] = fmaf(cx, w4.w, sacc[q * 4 + 3]);
            }
        }
    }

    // write partial s for this chunk (first pass: c = 0.1 uniform, folded here)
    const float mul = first ? 0.1f : 1.0f;
    float* sp = s_part + (((size_t)blockIdx.x * BATCH + b) * OO + o) * EE;
    #pragma unroll
    for (int q = 0; q < 4; ++q) {
        float4 t;
        t.x = mul * sacc[q * 4 + 0]; t.y = mul * sacc[q * 4 + 1];
        t.z = mul * sacc[q * 4 + 2]; t.w = mul * sacc[q * 4 + 3];
        reinterpret_cast<float4*>(sp)[q] = t;
    }
}

// squash kernel: reduce partial s over chunks, squash, update V (or write out).
// 4 waves/block split the 128-chunk reduction 4-way (32 chunks each), then
// LDS-reduce; wave 0 does the squash + store. 640 blocks keep it BW-bound.
__global__ __launch_bounds__(256) void caps_squash_kernel(
    const float* __restrict__ s_part,  // [NCHUNK][256][10][16]
    float* __restrict__ V,             // [256][10][16]
    float* __restrict__ out,           // [256][10][16]
    int accum, int last)
{
    __shared__ float red[3][64];
    const int lane = threadIdx.x & 63;
    const int w    = threadIdx.x >> 6;
    const int g    = blockIdx.x * 64 + lane;    // < 40960

    const float* sp = s_part + g;
    float s = 0.f;
    #pragma unroll 8
    for (int ch = w * (NCHUNK / 4); ch < (w + 1) * (NCHUNK / 4); ++ch)
        s += sp[(size_t)ch * (BATCH * OO * EE)];

    if (w > 0) red[w - 1][lane] = s;
    __syncthreads();
    if (w == 0) {
        s += red[0][lane] + red[1][lane] + red[2][lane];

        // squared norm over the 16-element e axis (lanes g..g+15 share (b,o))
        float sq = s * s;
        #pragma unroll
        for (int m = 1; m < 16; m <<= 1) sq += __shfl_xor(sq, m, 16);

        float scale = sq / (1.f + sq) / (sqrtf(sq) + 1e-6f);
        float v = scale * s;

        if (last)       out[g] = v;
        else if (accum) V[g]  += v;
        else            V[g]   = v;
    }
}

extern "C" void kernel_launch(void* const* d_in, const int* in_sizes, int n_in,
                              void* d_out, int out_size, void* d_ws, size_t ws_size,
                              hipStream_t stream) {
    const float* x = (const float*)d_in[0];   // [256,32,6,6,8]
    const float* W = (const float*)d_in[1];   // [1,32,6,6,10,8,16]
    float* out = (float*)d_out;               // [256,10,16]

    float* s_part = (float*)d_ws;                                   // NCHUNK*40960 floats
    float* V      = s_part + (size_t)NCHUNK * BATCH * OO * EE;      // 40960 floats

    dim3 grid(NCHUNK, NBT), blk(NT);
    const int sq_blocks = (BATCH * OO * EE) / 64;   // 640

    // iteration 1: b=0 -> c uniform 0.1; v1 -> V
    caps_pass_kernel<<<grid, blk, 0, stream>>>(x, W, V, s_part, 1);
    caps_squash_kernel<<<sq_blocks, 256, 0, stream>>>(s_part, V, out, 0, 0);
    // iteration 2: logits = dot(u_hat, v1); V += v2
    caps_pass_kernel<<<grid, blk, 0, stream>>>(x, W, V, s_part, 0);
    caps_squash_kernel<<<sq_blocks, 256, 0, stream>>>(s_part, V, out, 1, 0);
    // iteration 3 (final): logits = dot(u_hat, v1+v2); output v3
    caps_pass_kernel<<<grid, blk, 0, stream>>>(x, W, V, s_part, 0);
    caps_squash_kernel<<<sq_blocks, 256, 0, stream>>>(s_part, V, out, 0, 1);
}

// Round 8
// 166.326 us; speedup vs baseline: 1.8461x; 1.8461x over previous
//
#include <hip/hip_runtime.h>
#include <math.h>

// Problem constants
#define BATCH 256
#define IC    1152   // 32*6*6 input capsule positions
#define DD    8
#define OO    10
#define EE    16
#define BTILE 64     // batches per block (one wave per o, lanes = batch)
#define NBT   4      // BATCH / BTILE
#define NT    640    // OO * BTILE threads per block (10 waves)
#define CHUNK 9      // ijk positions per block
#define NCHUNK 128   // IC / CHUNK  -> 512 blocks = exactly 2 blocks/CU

// pass kernel, SINGLE-W-sweep + register-diet form.
// Cross-round evidence (r0-r7): scalar pipe streams W at ~50 x16-loads/us/CU
// (~3 B/cyc) -> floor ~12.8 us per sweep at this redundancy. r6 (43 us) pays
// 2 sweeps at 2-3 blocks/CU; r5 (64 us) paid 1 sweep but 68 VGPR -> 1
// block/CU (m69 tier: waves halve above 64) + 10 serializing barriers.
// This kernel combines: ONE W sweep (u[16] kept across the softmax barrier),
// <=64 VGPR via diet (V moved to LDS -16, xr array dropped -8), NO
// launch_bounds cap (r1/r3: caps force spills), 2 blocks/CU residency so
// the 10 barriers overlap across blocks.
//  - W from SGPRs (o wave-uniform via readfirstlane -> s_load x16 bursts).
//  - x staged once in LDS d-major (conflict-free); v staged in LDS
//    v_lds[o][e][bl] (logit reads: fixed e, lanes bl -> 2-way free).
//  - softmax: exp before barrier (logits bounded, proven r1-r7), exchange
//    exp(lg) via double-buffered elg_lds, ONE barrier per ijk.
//  Checks: VGPR<=64 (go/no-go), WRITE_SIZE ~21 MB, LDS 64.5 KB.
__global__ __launch_bounds__(NT) void caps_pass_kernel(
    const float* __restrict__ x,       // [256][1152][8]
    const float* __restrict__ W,       // [1152][10][8][16]
    const float* __restrict__ V,       // [256][10][16] accumulated v
    float* __restrict__ s_part,        // [NCHUNK][256][10][16]
    int first)
{
    __shared__ float x_lds[CHUNK][DD][BTILE];   // 18.4 KB, d-major
    __shared__ float v_lds[OO][EE][BTILE];      // 40 KB
    __shared__ float elg_lds[2][NT];            // 5 KB, double-buffered

    const int tid = threadIdx.x;
    const int o   = tid >> 6;        // wave id 0..9
    const int bl  = tid & 63;
    const int o_u = __builtin_amdgcn_readfirstlane(o);   // wave-uniform o
    const int b   = blockIdx.y * BTILE + bl;
    const int ijk0 = blockIdx.x * CHUNK;

    // ---- stage x: all CHUNK ijk tiles into LDS (coalesced float4) ----
    {
        const float* xgrp = x + (size_t)(blockIdx.y * BTILE) * (IC * DD);
        #pragma unroll 1
        for (int i = tid; i < CHUNK * BTILE * 2; i += NT) {
            const int lq = i & 1;            // which half of the 8 d's
            const int lb = (i >> 1) & 63;    // batch within tile
            const int ls = i >> 7;           // ijk within chunk
            const float4 t = *reinterpret_cast<const float4*>(
                xgrp + (size_t)lb * (IC * DD) + (size_t)(ijk0 + ls) * DD + lq * 4);
            x_lds[ls][lq * 4 + 0][lb] = t.x;
            x_lds[ls][lq * 4 + 1][lb] = t.y;
            x_lds[ls][lq * 4 + 2][lb] = t.z;
            x_lds[ls][lq * 4 + 3][lb] = t.w;
        }
    }

    // ---- stage v (routing passes only): V[b,o,:] -> v_lds[o][e][bl] ----
    if (!first) {
        const float4* vp = reinterpret_cast<const float4*>(V + ((size_t)b * OO + o) * EE);
        #pragma unroll
        for (int q = 0; q < 4; ++q) {
            const float4 t = vp[q];
            v_lds[o][q * 4 + 0][bl] = t.x;   // fixed e per store, lanes=bl:
            v_lds[o][q * 4 + 1][bl] = t.y;   // 2 lanes/bank -> free
            v_lds[o][q * 4 + 2][bl] = t.z;
            v_lds[o][q * 4 + 3][bl] = t.w;
        }
    }
    __syncthreads();

    float sacc[EE];
    #pragma unroll
    for (int e = 0; e < EE; ++e) sacc[e] = 0.f;

    int p = 0;
    #pragma unroll 1
    for (int s = 0; s < CHUNK; ++s) {
        const float* wp = W + (size_t)(ijk0 + s) * (OO * DD * EE) + o_u * (DD * EE);

        // u[e] = sum_d x_d * W[d][e]  -- the ONLY W sweep (s_load x16 bursts)
        float u[EE];
        #pragma unroll
        for (int e = 0; e < EE; ++e) u[e] = 0.f;
        #pragma unroll
        for (int d = 0; d < DD; ++d) {
            const float xv = x_lds[s][d][bl];   // transient, no xr[] array
            #pragma unroll
            for (int e = 0; e < EE; ++e)
                u[e] = fmaf(xv, wp[d * EE + e], u[e]);   // W from SGPR
        }

        float c;
        if (!first) {
            // logit from u with v out of LDS (saves 16 VGPR vs vreg[])
            float lg = 0.f;
            #pragma unroll
            for (int e = 0; e < EE; ++e)
                lg = fmaf(u[e], v_lds[o][e][bl], lg);
            const float elg = __expf(lg);   // bounded logits: no max-sub
            elg_lds[p][tid] = elg;
            __syncthreads();                 // one barrier per ijk
            float den = 0.f;
            #pragma unroll
            for (int oo = 0; oo < OO; ++oo)
                den += elg_lds[p][oo * 64 + bl];
            c = __fdividef(elg, den);
            p ^= 1;
        } else {
            c = 1.0f;   // uniform 0.1 folded into output mul
        }

        #pragma unroll
        for (int e = 0; e < EE; ++e)
            sacc[e] = fmaf(c, u[e], sacc[e]);
    }

    // write partial s for this chunk (first pass: c = 0.1 uniform, folded)
    const float mul = first ? 0.1f : 1.0f;
    float* sp = s_part + (((size_t)blockIdx.x * BATCH + b) * OO + o) * EE;
    #pragma unroll
    for (int q = 0; q < 4; ++q) {
        float4 t;
        t.x = mul * sacc[q * 4 + 0]; t.y = mul * sacc[q * 4 + 1];
        t.z = mul * sacc[q * 4 + 2]; t.w = mul * sacc[q * 4 + 3];
        reinterpret_cast<float4*>(sp)[q] = t;
    }
}

// squash kernel: reduce partial s over chunks, squash, update V (or write out).
// 4 waves/block split the 128-chunk reduction 4-way (32 chunks each), then
// LDS-reduce; wave 0 does the squash + store. 640 blocks keep it BW-bound.
__global__ __launch_bounds__(256) void caps_squash_kernel(
    const float* __restrict__ s_part,  // [NCHUNK][256][10][16]
    float* __restrict__ V,             // [256][10][16]
    float* __restrict__ out,           // [256][10][16]
    int accum, int last)
{
    __shared__ float red[3][64];
    const int lane = threadIdx.x & 63;
    const int w    = threadIdx.x >> 6;
    const int g    = blockIdx.x * 64 + lane;    // < 40960

    const float* sp = s_part + g;
    float s = 0.f;
    #pragma unroll 8
    for (int ch = w * (NCHUNK / 4); ch < (w + 1) * (NCHUNK / 4); ++ch)
        s += sp[(size_t)ch * (BATCH * OO * EE)];

    if (w > 0) red[w - 1][lane] = s;
    __syncthreads();
    if (w == 0) {
        s += red[0][lane] + red[1][lane] + red[2][lane];

        // squared norm over the 16-element e axis (lanes g..g+15 share (b,o))
        float sq = s * s;
        #pragma unroll
        for (int m = 1; m < 16; m <<= 1) sq += __shfl_xor(sq, m, 16);

        float scale = sq / (1.f + sq) / (sqrtf(sq) + 1e-6f);
        float v = scale * s;

        if (last)       out[g] = v;
        else if (accum) V[g]  += v;
        else            V[g]   = v;
    }
}

extern "C" void kernel_launch(void* const* d_in, const int* in_sizes, int n_in,
                              void* d_out, int out_size, void* d_ws, size_t ws_size,
                              hipStream_t stream) {
    const float* x = (const float*)d_in[0];   // [256,32,6,6,8]
    const float* W = (const float*)d_in[1];   // [1,32,6,6,10,8,16]
    float* out = (float*)d_out;               // [256,10,16]

    float* s_part = (float*)d_ws;                                   // NCHUNK*40960 floats
    float* V      = s_part + (size_t)NCHUNK * BATCH * OO * EE;      // 40960 floats

    dim3 grid(NCHUNK, NBT), blk(NT);
    const int sq_blocks = (BATCH * OO * EE) / 64;   // 640

    // iteration 1: b=0 -> c uniform 0.1; v1 -> V
    caps_pass_kernel<<<grid, blk, 0, stream>>>(x, W, V, s_part, 1);
    caps_squash_kernel<<<sq_blocks, 256, 0, stream>>>(s_part, V, out, 0, 0);
    // iteration 2: logits = dot(u_hat, v1); V += v2
    caps_pass_kernel<<<grid, blk, 0, stream>>>(x, W, V, s_part, 0);
    caps_squash_kernel<<<sq_blocks, 256, 0, stream>>>(s_part, V, out, 1, 0);
    // iteration 3 (final): logits = dot(u_hat, v1+v2); output v3
    caps_pass_kernel<<<grid, blk, 0, stream>>>(x, W, V, s_part, 0);
    caps_squash_kernel<<<sq_blocks, 256, 0, stream>>>(s_part, V, out, 0, 1);
}